// Round 2
// baseline (436.871 us; speedup 1.0000x reference)
//
#include <hip/hip_runtime.h>
#include <hip/hip_bf16.h>
#include <stdint.h>

#define DIM   3072
#define BATCH 16384

typedef __attribute__((ext_vector_type(8))) short bf16x8;
typedef __attribute__((ext_vector_type(4))) float f32x4;

// f32 -> bf16 round-to-nearest-even (inputs are finite; no NaN handling needed)
__device__ __forceinline__ unsigned short f2b(float f) {
    union { float f; unsigned u; } c; c.f = f;
    unsigned u = c.u;
    unsigned r = (u + 0x7fffu + ((u >> 16) & 1u)) >> 16;
    return (unsigned short)r;
}

// ---------------- pre-pass: x (f32) -> xb (bf16), vectorized ----------------
__global__ void cvt_x_kernel(const float* __restrict__ x, ushort* __restrict__ xb, int n4) {
    int stride = gridDim.x * blockDim.x;
    for (int i = blockIdx.x * blockDim.x + threadIdx.x; i < n4; i += stride) {
        float4 v = reinterpret_cast<const float4*>(x)[i];
        ushort4 o;
        o.x = f2b(v.x); o.y = f2b(v.y); o.z = f2b(v.z); o.w = f2b(v.w);
        reinterpret_cast<ushort4*>(xb)[i] = o;
    }
}

// ------ pre-pass: Wt[u][d] = bf16(mask[u][d] * w[d][u]), LDS-tiled transpose ------
__global__ void build_wt_kernel(const float* __restrict__ w, const float* __restrict__ mask,
                                ushort* __restrict__ wt) {
    __shared__ float tile[64][65];
    const int u0 = blockIdx.x * 64;
    const int d0 = blockIdx.y * 64;
    const int t  = threadIdx.x;
    const int rr = t >> 4, cc = t & 15;
#pragma unroll
    for (int it = 0; it < 4; ++it) {
        int drow = it * 16 + rr;
        float4 v = *reinterpret_cast<const float4*>(&w[(size_t)(d0 + drow) * DIM + u0 + cc * 4]);
        tile[drow][cc * 4 + 0] = v.x;
        tile[drow][cc * 4 + 1] = v.y;
        tile[drow][cc * 4 + 2] = v.z;
        tile[drow][cc * 4 + 3] = v.w;
    }
    __syncthreads();
#pragma unroll
    for (int it = 0; it < 4; ++it) {
        int urow = it * 16 + rr;
        float4 mv = *reinterpret_cast<const float4*>(&mask[(size_t)(u0 + urow) * DIM + d0 + cc * 4]);
        ushort4 o;
        o.x = f2b(tile[cc * 4 + 0][urow] * mv.x);
        o.y = f2b(tile[cc * 4 + 1][urow] * mv.y);
        o.z = f2b(tile[cc * 4 + 2][urow] * mv.z);
        o.w = f2b(tile[cc * 4 + 3][urow] * mv.w);
        *reinterpret_cast<ushort4*>(&wt[(size_t)(u0 + urow) * DIM + d0 + cc * 4]) = o;
    }
}

// ---------------- GEMM: C = xb @ Wt^T + bias  (m97 structure) ----------------
// A (xb): [BATCH][DIM] bf16 row-major.  Bt (Wt): [N=DIM][K=DIM] bf16 row-major.
#define GLOAD_LDS16(g, l)                                                                 \
    __builtin_amdgcn_global_load_lds((const __attribute__((address_space(1))) void*)(g),  \
                                     (__attribute__((address_space(3))) void*)(l), 16, 0, 0)

template<bool XB16>
__global__ __launch_bounds__(256) void gemm_kernel(const void* __restrict__ Av,
                                                   const ushort* __restrict__ Bt,
                                                   const float* __restrict__ bias,
                                                   float* __restrict__ C) {
    constexpr int BM = 128, BN = 128, BK = 32;
    __shared__ ushort As[BM * BK]; // [m][k], 8 KB
    __shared__ ushort Bs[BN * BK]; // [n][k], 8 KB
    const int tid  = threadIdx.x;
    const int lane = tid & 63;
    const int wid  = tid >> 6;       // 4 waves: 2x2 sub-tiles of 64x64
    const int wr = wid >> 1, wc = wid & 1;
    const int brow = blockIdx.y * BM;
    const int bcol = blockIdx.x * BN;
    const int r16 = lane & 15, kg = lane >> 4;

    const ushort* Ab = (const ushort*)Av;
    const float*  Af = (const float*)Av;

    f32x4 acc[4][4] = {};

    for (int k0 = 0; k0 < DIM; k0 += BK) {
        // ---- stage A ----
        if constexpr (XB16) {
#pragma unroll
            for (int c = 0; c < 2; ++c) {
                int q = wid * 2 + c;                 // 1KB chunk index (0..7)
                int row = q * 16 + (lane >> 2);
                const ushort* gp = Ab + (size_t)(brow + row) * DIM + k0 + (lane & 3) * 8;
                GLOAD_LDS16(gp, As + q * 512);
            }
        } else {
            // reg-stage f32 -> bf16 (ws-too-small fallback)
#pragma unroll
            for (int p = 0; p < 4; ++p) {
                int row = p * 32 + (tid >> 3);
                int f4  = tid & 7;
                float4 v = *reinterpret_cast<const float4*>(
                    &Af[(size_t)(brow + row) * DIM + k0 + f4 * 4]);
                ushort4 o; o.x = f2b(v.x); o.y = f2b(v.y); o.z = f2b(v.z); o.w = f2b(v.w);
                *reinterpret_cast<ushort4*>(&As[row * BK + f4 * 4]) = o;
            }
        }
        // ---- stage B ----
#pragma unroll
        for (int c = 0; c < 2; ++c) {
            int q = wid * 2 + c;
            int row = q * 16 + (lane >> 2);
            const ushort* gp = Bt + (size_t)(bcol + row) * DIM + k0 + (lane & 3) * 8;
            GLOAD_LDS16(gp, Bs + q * 512);
        }
        __syncthreads();   // compiler drains vmcnt/lgkmcnt before s_barrier

        // ---- compute: 16 MFMA per K-step ----
        bf16x8 a[4], b[4];
#pragma unroll
        for (int i = 0; i < 4; ++i)
            a[i] = *reinterpret_cast<const bf16x8*>(&As[(wr * 64 + i * 16 + r16) * BK + kg * 8]);
#pragma unroll
        for (int j = 0; j < 4; ++j)
            b[j] = *reinterpret_cast<const bf16x8*>(&Bs[(wc * 64 + j * 16 + r16) * BK + kg * 8]);
#pragma unroll
        for (int i = 0; i < 4; ++i)
#pragma unroll
            for (int j = 0; j < 4; ++j)
                acc[i][j] = __builtin_amdgcn_mfma_f32_16x16x32_bf16(a[i], b[j], acc[i][j], 0, 0, 0);
        __syncthreads();
    }

    // ---- epilogue: C/D layout col=lane&15, row=(lane>>4)*4+r ----
#pragma unroll
    for (int j = 0; j < 4; ++j) {
        int col = bcol + wc * 64 + j * 16 + r16;
        float bv = bias[col];
#pragma unroll
        for (int i = 0; i < 4; ++i) {
            int row0 = brow + wr * 64 + i * 16 + kg * 4;
#pragma unroll
            for (int r = 0; r < 4; ++r)
                C[(size_t)(row0 + r) * DIM + col] = acc[i][j][r] + bv;
        }
    }
}

extern "C" void kernel_launch(void* const* d_in, const int* in_sizes, int n_in,
                              void* d_out, int out_size, void* d_ws, size_t ws_size,
                              hipStream_t stream) {
    const float* x    = (const float*)d_in[0];
    const float* w    = (const float*)d_in[1];
    const float* bias = (const float*)d_in[2];
    const float* mask = (const float*)d_in[3];
    float* out = (float*)d_out;

    const size_t wt_bytes = (size_t)DIM * DIM * sizeof(ushort);
    const size_t xb_off   = (wt_bytes + 255) & ~(size_t)255;
    const size_t xb_bytes = (size_t)BATCH * DIM * sizeof(ushort);

    ushort* wt = (ushort*)d_ws;
    ushort* xb = (ushort*)((char*)d_ws + xb_off);

    build_wt_kernel<<<dim3(DIM / 64, DIM / 64), 256, 0, stream>>>(w, mask, wt);

    if (ws_size >= xb_off + xb_bytes) {
        cvt_x_kernel<<<2048, 256, 0, stream>>>(x, xb, BATCH * DIM / 4);
        gemm_kernel<true><<<dim3(DIM / 128, BATCH / 128), 256, 0, stream>>>(xb, wt, bias, out);
    } else {
        gemm_kernel<false><<<dim3(DIM / 128, BATCH / 128), 256, 0, stream>>>(x, wt, bias, out);
    }
}

// Round 3
// 350.441 us; speedup vs baseline: 1.2466x; 1.2466x over previous
//
#include <hip/hip_runtime.h>
#include <hip/hip_bf16.h>
#include <stdint.h>

#define DIM   3072
#define BATCH 16384

typedef __attribute__((ext_vector_type(8))) short bf16x8;
typedef __attribute__((ext_vector_type(4))) float f32x4;

__device__ __forceinline__ unsigned short f2b(float f) {
    union { float f; unsigned u; } c; c.f = f;
    unsigned u = c.u;
    unsigned r = (u + 0x7fffu + ((u >> 16) & 1u)) >> 16;
    return (unsigned short)r;
}

// ---------------- pre-pass: x (f32) -> xb (bf16) ----------------
__global__ void cvt_x_kernel(const float* __restrict__ x, ushort* __restrict__ xb, int n4) {
    int stride = gridDim.x * blockDim.x;
    for (int i = blockIdx.x * blockDim.x + threadIdx.x; i < n4; i += stride) {
        float4 v = reinterpret_cast<const float4*>(x)[i];
        ushort4 o;
        o.x = f2b(v.x); o.y = f2b(v.y); o.z = f2b(v.z); o.w = f2b(v.w);
        reinterpret_cast<ushort4*>(xb)[i] = o;
    }
}

// ------ pre-pass: Wt[u][d] = bf16(mask[u][d] * w[d][u]) ------
__global__ void build_wt_kernel(const float* __restrict__ w, const float* __restrict__ mask,
                                ushort* __restrict__ wt) {
    __shared__ float tile[64][65];
    const int u0 = blockIdx.x * 64;
    const int d0 = blockIdx.y * 64;
    const int t  = threadIdx.x;
    const int rr = t >> 4, cc = t & 15;
#pragma unroll
    for (int it = 0; it < 4; ++it) {
        int drow = it * 16 + rr;
        float4 v = *reinterpret_cast<const float4*>(&w[(size_t)(d0 + drow) * DIM + u0 + cc * 4]);
        tile[drow][cc * 4 + 0] = v.x;
        tile[drow][cc * 4 + 1] = v.y;
        tile[drow][cc * 4 + 2] = v.z;
        tile[drow][cc * 4 + 3] = v.w;
    }
    __syncthreads();
#pragma unroll
    for (int it = 0; it < 4; ++it) {
        int urow = it * 16 + rr;
        float4 mv = *reinterpret_cast<const float4*>(&mask[(size_t)(u0 + urow) * DIM + d0 + cc * 4]);
        ushort4 o;
        o.x = f2b(tile[cc * 4 + 0][urow] * mv.x);
        o.y = f2b(tile[cc * 4 + 1][urow] * mv.y);
        o.z = f2b(tile[cc * 4 + 2][urow] * mv.z);
        o.w = f2b(tile[cc * 4 + 3][urow] * mv.w);
        *reinterpret_cast<ushort4*>(&wt[(size_t)(u0 + urow) * DIM + d0 + cc * 4]) = o;
    }
}

#define GLOAD_LDS16(g, l)                                                                 \
    __builtin_amdgcn_global_load_lds((const __attribute__((address_space(1))) void*)(g),  \
                                     (__attribute__((address_space(3))) void*)(l), 16, 0, 0)

// ---------------- fallback (ws too small): 128² f32 reg-staging ----------------
__global__ __launch_bounds__(256) void gemm_f32_kernel(const float* __restrict__ Af,
                                                       const ushort* __restrict__ Bt,
                                                       const float* __restrict__ bias,
                                                       float* __restrict__ C) {
    constexpr int BK = 32;
    __shared__ ushort As[128 * BK];
    __shared__ ushort Bs[128 * BK];
    const int tid  = threadIdx.x;
    const int lane = tid & 63;
    const int wid  = tid >> 6;
    const int wr = wid >> 1, wc = wid & 1;
    const int brow = blockIdx.y * 128;
    const int bcol = blockIdx.x * 128;
    const int r16 = lane & 15, kg = lane >> 4;
    f32x4 acc[4][4] = {};
    for (int k0 = 0; k0 < DIM; k0 += BK) {
#pragma unroll
        for (int p = 0; p < 4; ++p) {
            int row = p * 32 + (tid >> 3);
            int f4  = tid & 7;
            float4 v = *reinterpret_cast<const float4*>(
                &Af[(size_t)(brow + row) * DIM + k0 + f4 * 4]);
            ushort4 o; o.x = f2b(v.x); o.y = f2b(v.y); o.z = f2b(v.z); o.w = f2b(v.w);
            *reinterpret_cast<ushort4*>(&As[row * BK + f4 * 4]) = o;
        }
#pragma unroll
        for (int c = 0; c < 2; ++c) {
            int q = wid * 2 + c;
            int row = q * 16 + (lane >> 2);
            const ushort* gp = Bt + (size_t)(bcol + row) * DIM + k0 + (lane & 3) * 8;
            GLOAD_LDS16(gp, Bs + q * 512);
        }
        __syncthreads();
        bf16x8 a[4], b[4];
#pragma unroll
        for (int i = 0; i < 4; ++i)
            a[i] = *reinterpret_cast<const bf16x8*>(&As[(wr * 64 + i * 16 + r16) * BK + kg * 8]);
#pragma unroll
        for (int j = 0; j < 4; ++j)
            b[j] = *reinterpret_cast<const bf16x8*>(&Bs[(wc * 64 + j * 16 + r16) * BK + kg * 8]);
#pragma unroll
        for (int i = 0; i < 4; ++i)
#pragma unroll
            for (int j = 0; j < 4; ++j)
                acc[i][j] = __builtin_amdgcn_mfma_f32_16x16x32_bf16(a[i], b[j], acc[i][j], 0, 0, 0);
        __syncthreads();
    }
#pragma unroll
    for (int j = 0; j < 4; ++j) {
        int col = bcol + wc * 64 + j * 16 + r16;
        float bv = bias[col];
#pragma unroll
        for (int i = 0; i < 4; ++i) {
            int row0 = brow + wr * 64 + i * 16 + kg * 4;
#pragma unroll
            for (int r = 0; r < 4; ++r)
                C[(size_t)(row0 + r) * DIM + col] = acc[i][j][r] + bv;
        }
    }
}

// ======================= 256² 8-phase bf16 GEMM =======================
// A: xb [BATCH][DIM] bf16.  B: wt [DIM][DIM] bf16 (row = output col, col = k).
// 8 waves (2M x 4N), per-wave C = 128x64. BK=64, double-buffered 128 KB LDS.
// LDS swizzle: 16B-granule XOR with (row&7); applied on pre-swizzled global
// source (linear global_load_lds dest) and on ds_read address.
__global__ __launch_bounds__(512, 1) void gemm8p(const ushort* __restrict__ A,
                                                 const ushort* __restrict__ B,
                                                 const float* __restrict__ bias,
                                                 float* __restrict__ C) {
    __shared__ ushort sh[2 * 2 * 16384];   // [buf][side A=0/B=1][256][64] : 128 KB

    const int tid  = threadIdx.x;
    const int lane = tid & 63;
    const int wid  = tid >> 6;   // 0..7
    const int wr   = wid >> 2;   // 0..1  (M)
    const int wc   = wid & 3;    // 0..3  (N)
    const int l15  = lane & 15;
    const int kg   = lane >> 4;
    const int sx   = lane & 7;   // swizzle XOR key on ds_read (row&7 == lane&7)

    // staging lane constants: lane -> (row-in-chunk, logical granule)
    const int srow = lane >> 3;            // 0..7
    const int sg   = (lane & 7) ^ srow;    // pre-swizzled source granule

    // XCD-aware bijective swizzle (gridDim.x == 768, %8 == 0)
    const int orig = blockIdx.x;
    const int wg   = (orig & 7) * (gridDim.x >> 3) + (orig >> 3);
    const int tm   = wg / 12;
    const int tn   = wg - tm * 12;
    const int brow = tm * 256, bcol = tn * 256;

    f32x4 acc[8][4] = {};
    bf16x8 a_[8], b0_[4], b1_[4];

    // stage half-tile h (128 rows) of tile tt into buf b, side (0=A,1=B).
    // 2 x global_load_lds (16B) per thread; LDS dest linear, source pre-swizzled.
#define STAGE(b, side, h, tt)                                                              \
    do {                                                                                   \
        int _t = (tt) < 47 ? (tt) : 47;                                                    \
        const ushort* _base = (side) ? B : A;                                              \
        int _r0 = ((side) ? bcol : brow) + (h) * 128 + wid * 16 + srow;                    \
        const ushort* _g0 = _base + (size_t)_r0 * DIM + _t * 64 + sg * 8;                  \
        ushort* _l0 = sh + ((b) * 2 + (side)) * 16384 + (h) * 8192 + wid * 1024;           \
        GLOAD_LDS16(_g0, _l0);                                                             \
        GLOAD_LDS16(_g0 + (size_t)8 * DIM, _l0 + 512);                                     \
    } while (0)

#define LDA(QB, QM)                                                                        \
    _Pragma("unroll") for (int fm = 0; fm < 4; ++fm)                                       \
    _Pragma("unroll") for (int ks = 0; ks < 2; ++ks)                                       \
        a_[fm * 2 + ks] = *reinterpret_cast<const bf16x8*>(                                \
            sh + (QB) * 32768 + (wr * 128 + (QM) * 64 + fm * 16 + l15) * 64 +              \
            (((ks * 4 + kg) ^ sx) * 8));

#define LDB(DST, QB, QN)                                                                   \
    _Pragma("unroll") for (int fn = 0; fn < 2; ++fn)                                       \
    _Pragma("unroll") for (int ks = 0; ks < 2; ++ks)                                       \
        DST[fn * 2 + ks] = *reinterpret_cast<const bf16x8*>(                               \
            sh + (QB) * 32768 + 16384 + (wc * 64 + (QN) * 32 + fn * 16 + l15) * 64 +       \
            (((ks * 4 + kg) ^ sx) * 8));

#define MMQ(QM, QN, BARR)                                                                  \
    _Pragma("unroll") for (int fm = 0; fm < 4; ++fm)                                       \
    _Pragma("unroll") for (int fn = 0; fn < 2; ++fn)                                       \
    _Pragma("unroll") for (int ks = 0; ks < 2; ++ks)                                       \
        acc[(QM) * 4 + fm][(QN) * 2 + fn] = __builtin_amdgcn_mfma_f32_16x16x32_bf16(       \
            a_[fm * 2 + ks], BARR[fn * 2 + ks], acc[(QM) * 4 + fm][(QN) * 2 + fn], 0, 0, 0);

#define MIDSYNC()                                                                          \
    __builtin_amdgcn_s_barrier();                                                          \
    asm volatile("s_waitcnt lgkmcnt(0)" ::: "memory");                                     \
    __builtin_amdgcn_sched_barrier(0);                                                     \
    __builtin_amdgcn_s_setprio(1);

#define ENDPHASE()                                                                         \
    __builtin_amdgcn_s_setprio(0);                                                         \
    __builtin_amdgcn_s_barrier();

    // ---- prologue: tile0 fully, B-halves of tile1; leave t1.B in flight ----
    STAGE(0, 0, 0, 0);
    STAGE(0, 0, 1, 0);
    STAGE(0, 1, 0, 0);
    STAGE(0, 1, 1, 0);
    STAGE(1, 1, 0, 1);
    STAGE(1, 1, 1, 1);
    asm volatile("s_waitcnt vmcnt(4)" ::: "memory");
    __builtin_amdgcn_s_barrier();

    // ---- main loop: 2 K-tiles (t even: buf0 = t, buf1 = t+1), 8 phases ----
    for (int t = 0; t < 48; t += 2) {
        // phase 1: tile t, Q(0,0)            stage A0(t+1) -> buf1
        LDA(0, 0); LDB(b0_, 0, 0);
        STAGE(1, 0, 0, t + 1);
        MIDSYNC(); MMQ(0, 0, b0_); ENDPHASE();
        // phase 2: Q(0,1)                    stage A1(t+1) -> buf1
        LDB(b1_, 0, 1);
        STAGE(1, 0, 1, t + 1);
        MIDSYNC(); MMQ(0, 1, b1_); ENDPHASE();
        // phase 3: Q(1,0)                    stage B0(t+2) -> buf0
        LDA(0, 1);
        STAGE(0, 1, 0, t + 2);
        MIDSYNC(); MMQ(1, 0, b0_); ENDPHASE();
        // phase 4: Q(1,1)                    stage B1(t+2) -> buf0, vmcnt
        STAGE(0, 1, 1, t + 2);
        asm volatile("s_waitcnt vmcnt(4)" ::: "memory");
        MIDSYNC(); MMQ(1, 1, b1_); ENDPHASE();
        // phase 5: tile t+1, Q(0,0)          stage A0(t+2) -> buf0
        LDA(1, 0); LDB(b0_, 1, 0);
        STAGE(0, 0, 0, t + 2);
        MIDSYNC(); MMQ(0, 0, b0_); ENDPHASE();
        // phase 6: Q(0,1)                    stage A1(t+2) -> buf0
        LDB(b1_, 1, 1);
        STAGE(0, 0, 1, t + 2);
        MIDSYNC(); MMQ(0, 1, b1_); ENDPHASE();
        // phase 7: Q(1,0)                    stage B0(t+3) -> buf1
        LDA(1, 1);
        STAGE(1, 1, 0, t + 3);
        MIDSYNC(); MMQ(1, 0, b0_); ENDPHASE();
        // phase 8: Q(1,1)                    stage B1(t+3) -> buf1, vmcnt
        STAGE(1, 1, 1, t + 3);
        asm volatile("s_waitcnt vmcnt(4)" ::: "memory");
        MIDSYNC(); MMQ(1, 1, b1_); ENDPHASE();
    }

    // ---- epilogue: C/D layout col=lane&15, row=(lane>>4)*4+r ----
#pragma unroll
    for (int n = 0; n < 4; ++n) {
        int col = bcol + wc * 64 + n * 16 + l15;
        float bv = bias[col];
#pragma unroll
        for (int m = 0; m < 8; ++m) {
            int row0 = brow + wr * 128 + m * 16 + kg * 4;
#pragma unroll
            for (int r = 0; r < 4; ++r)
                C[(size_t)(row0 + r) * DIM + col] = acc[m][n][r] + bv;
        }
    }
#undef STAGE
#undef LDA
#undef LDB
#undef MMQ
#undef MIDSYNC
#undef ENDPHASE
}

extern "C" void kernel_launch(void* const* d_in, const int* in_sizes, int n_in,
                              void* d_out, int out_size, void* d_ws, size_t ws_size,
                              hipStream_t stream) {
    const float* x    = (const float*)d_in[0];
    const float* w    = (const float*)d_in[1];
    const float* bias = (const float*)d_in[2];
    const float* mask = (const float*)d_in[3];
    float* out = (float*)d_out;

    const size_t wt_bytes = (size_t)DIM * DIM * sizeof(ushort);
    const size_t xb_off   = (wt_bytes + 255) & ~(size_t)255;
    const size_t xb_bytes = (size_t)BATCH * DIM * sizeof(ushort);

    ushort* wt = (ushort*)d_ws;
    ushort* xb = (ushort*)((char*)d_ws + xb_off);

    build_wt_kernel<<<dim3(DIM / 64, DIM / 64), 256, 0, stream>>>(w, mask, wt);

    if (ws_size >= xb_off + xb_bytes) {
        cvt_x_kernel<<<2048, 256, 0, stream>>>(x, xb, BATCH * DIM / 4);
        gemm8p<<<(BATCH / 256) * (DIM / 256), 512, 0, stream>>>(xb, wt, bias, out);
    } else {
        gemm_f32_kernel<<<dim3(DIM / 128, BATCH / 128), 256, 0, stream>>>(x, wt, bias, out);
    }
}